// Round 7
// baseline (159.801 us; speedup 1.0000x reference)
//
#include <hip/hip_runtime.h>
#include <math.h>

#define NELEC 10
#define NSPIN 2
#define NPER 5
#define DIM 3
#define NION 2
#define DP 32
#define NDENSE 64
#define NPERM 120
#define RS 324   // G row stride (words): the 5 selectable rows land on disjoint bank quads.
#define HTS 124  // HT row stride (words): reads 2 addrs/bank-quad (free, m136); writes 2/bank free.
#define KQ 16    // k-rows parked per quarter (R17-validated structure)

// R22: per-spin LDS pool, all regions coexist (R17 layout + w1L staging region):
//   s1e[160] @ 0, G[5][324] @ 160..1780, w1L[64][64] @ 1780..5876, HTQ[16][124] @ 5876..7860
// Pool/spin = 31440 B -> block total 62880 B (< 64 KB static limit) -> 2 WGs/CU.
// WHY: R21 proved the compiler defeats latency-pipelining (VGPR stayed 116) and R17/R20
// proved occupancy/barriers are non-levers. Remaining theory: the GEMM's per-k w1
// global loads (2 x 1KB wave-loads/k) saturate the CU-shared vmem/L1 pipe (~64B/cy
// -> 256 cy/k/CU vs 144 cy/k VALU). Fix: w1 -> LDS once (16KB/spin), GEMM reads it as
// 8-lane-broadcast ds_read_b128 (2-way bank aliasing = free), taking the w1 stream off
// the shared vmem pipe entirely.
#define W1OFF (160 + NPER * RS)               // 1780
#define HTQOFF (W1OFF + NDENSE * NDENSE)      // 5876
#define POOL_WORDS (HTQOFF + KQ * HTS)        // 7860

typedef float v2f __attribute__((ext_vector_type(2)));
typedef float v4f __attribute__((ext_vector_type(4)));

// Packed fp32 FMA (VOP3P), bit-identical to scalar v_fma pairs (R12-validated).
#define PK_FMA_LO(acc, hp, wp) \
    asm("v_pk_fma_f32 %0, %1, %2, %0 op_sel_hi:[1,0,1]" : "+v"(acc) : "v"(hp), "v"(wp))
#define PK_FMA_HI(acc, hp, wp) \
    asm("v_pk_fma_f32 %0, %1, %2, %0 op_sel:[0,1,0] op_sel_hi:[1,1,1]" : "+v"(acc) : "v"(hp), "v"(wp))

// tanh(x) = 1 - 2*rcp(exp(2x)+1): ~1-2 ulp, exact at saturation. Validated R5-R21.
__device__ __forceinline__ float fast_tanh(float x) {
    float e = __expf(2.0f * x);
    return 1.0f - 2.0f * __builtin_amdgcn_rcpf(e + 1.0f);
}

__device__ __forceinline__ unsigned pick_remove(unsigned& el, int d) {
    unsigned v = (el >> (4 * d)) & 0xFu;
    unsigned low = el & ((1u << (4 * d)) - 1u);
    el = low | ((el >> (4 * (d + 1))) << (4 * d));
    return v;
}

// ---------------- fused: one block per batch element, 4 waves = 2 spin-pairs ----------------
// Base = R17 (104us measured, VGPR 76, no spill). ONE change: gemm quarters read w1
// from LDS (w1L) instead of global. Per-element arithmetic order identical to R17/R13.
__global__ __launch_bounds__(256, 1) __attribute__((amdgpu_num_vgpr(128)))
void antisym_fused(
    const float* __restrict__ elec_pos, const float* __restrict__ ion_pos,
    const float* __restrict__ bf_w, const float* __restrict__ bf_b,
    const float* __restrict__ w0, const float* __restrict__ b0,
    const float* __restrict__ w1, const float* __restrict__ b1,
    const float* __restrict__ w2, const float* __restrict__ jk,
    float* __restrict__ out, int B)
{
    const int b = blockIdx.x;
    const int t = threadIdx.x;
    const int s = t >> 7;                   // spin: waves 0-1 -> 0, waves 2-3 -> 1
    const int ts = t & 127;                 // thread within the spin-pair
    const int wave = (t >> 6) & 1;          // wave within the spin-pair
    const int lane = t & 63;

    __shared__ __align__(16) float pool[NSPIN][POOL_WORDS];   // 2 x 31440 B
    __shared__ double red_h[NSPIN][2];
    __shared__ double red_j[NSPIN][2];
    __shared__ float jterm[2 * NELEC];

    float* s1e = pool[s];                                     // [160]
    #define GROW(j)   (pool[s] + 160 + (j) * RS)              // G[j][.]
    float* w1L = pool[s] + W1OFF;                             // [64][64] this spin's W1
    #define HTQROW(k) (pool[s] + HTQOFF + (k) * HTS)          // HTQ[k][.], k in [0,16)

    // ---- stage 1: stream_1e = tanh(feats @ bf_w + bf_b), this spin's 5 electrons ----
    const float* ep = elec_pos + (b * NELEC + s * NPER) * DIM;
    const float i0x = ion_pos[0], i0y = ion_pos[1], i0z = ion_pos[2];
    const float i1x = ion_pos[3], i1y = ion_pos[4], i1z = ion_pos[5];
    for (int idx = ts; idx < NPER * DP; idx += 128) {
        int j = idx >> 5, c = idx & 31;
        float ex = ep[j * 3 + 0], ey = ep[j * 3 + 1], ez = ep[j * 3 + 2];
        float dx0 = ex - i0x, dy0 = ey - i0y, dz0 = ez - i0z;
        float dx1 = ex - i1x, dy1 = ey - i1y, dz1 = ez - i1z;
        float n0 = sqrtf(dx0 * dx0 + dy0 * dy0 + dz0 * dz0);
        float n1 = sqrtf(dx1 * dx1 + dy1 * dy1 + dz1 * dz1);
        float acc = bf_b[c];
        acc += dx0 * bf_w[0 * DP + c];
        acc += dy0 * bf_w[1 * DP + c];
        acc += dz0 * bf_w[2 * DP + c];
        acc += dx1 * bf_w[3 * DP + c];
        acc += dy1 * bf_w[4 * DP + c];
        acc += dz1 * bf_w[5 * DP + c];
        acc += n0 * bf_w[6 * DP + c];
        acc += n1 * bf_w[7 * DP + c];
        s1e[idx] = fast_tanh(acc);
    }
    // w1 -> LDS staging (R19-proven code): 8 float4 per thread, L2-hot across blocks
    {
        const float* w1g = w1 + s * NDENSE * NDENSE;
        for (int idx = ts; idx < (NDENSE * NDENSE) / 4; idx += 128)
            ((float4*)w1L)[idx] = ((const float4*)w1g)[idx];
    }
    // jastrow terms (combine's exact per-term math; summed e-major by t0 later)
    if (t < 2 * NELEC) {
        int e = t >> 1, ion = t & 1;
        const float* epb = elec_pos + b * NELEC * DIM;
        float ex = epb[e * 3 + 0], ey = epb[e * 3 + 1], ez = epb[e * 3 + 2];
        float ix = ion_pos[ion * 3 + 0], iy = ion_pos[ion * 3 + 1], iz = ion_pos[ion * 3 + 2];
        float dx = ex - ix, dy = ey - iy, dz = ez - iz;
        jterm[t] = jk[ion] * sqrtf(dx * dx + dy * dy + dz * dz);
    }
    __syncthreads();

    // ---- stage 2: G[j][i*64+c] = s1e[j][:] @ w0[s][32i:32i+32, c] ----
    // Slice-outer with wcol[32] in registers (R14-validated): 96 global loads/wave.
    const float* w0s = w0 + s * (NPER * DP) * NDENSE;   // [160][64]
    #pragma unroll
    for (int m = 0; m < 3; m++) {
        const int i = wave + 2 * m;         // wave0: i=0,2,4  wave1: i=1,3 (m=2 skipped)
        if (i < NPER) {                     // wave-uniform branch
            float wcol[DP];
            #pragma unroll
            for (int k = 0; k < DP; k++) wcol[k] = w0s[(i * DP + k) * NDENSE + lane];
            #pragma unroll
            for (int j = 0; j < NPER; j++) {
                float acc = 0.f;
                #pragma unroll
                for (int q = 0; q < 8; q++) {
                    float4 sv = *(const float4*)(s1e + j * DP + q * 4);   // LDS broadcast
                    acc += sv.x * wcol[q * 4 + 0];
                    acc += sv.y * wcol[q * 4 + 1];
                    acc += sv.z * wcol[q * 4 + 2];
                    acc += sv.w * wcol[q * 4 + 3];
                }
                GROW(j)[i * NDENSE + lane] = acc;
            }
        }
    }
    __syncthreads();

    const float* b0s = b0 + s * NDENSE;
    const float* w2s = w2 + s * NDENSE;     // w2 is [s][64][1]
    const float* b1s = b1 + s * NDENSE;

    // ---- stage 3: lane = perm (phase 1) interleaved with 8x8-tile GEMM (phase 2),
    //      split into 4 k-quarters so only 16 HT rows are ever parked at once ----
    const int pid = wave * 60 + lane;
    float sign = 0.f;
    int p0 = 0, p1 = 0, p2 = 0, p3 = 0, p4 = 0;
    if (lane < 60) {
        int p = pid;
        unsigned el = 0x43210u;
        int d0 = p / 24; p -= d0 * 24;
        int d1 = p / 6;  p -= d1 * 6;
        int d2 = p / 2;  p -= d2 * 2;
        int d3 = p;
        p0 = pick_remove(el, d0);
        p1 = pick_remove(el, d1);
        p2 = pick_remove(el, d2);
        p3 = pick_remove(el, d3);
        p4 = el & 0xF;
        sign = ((d0 + d1 + d2 + d3) & 1) ? -1.f : 1.f;
    }
    const float* g0 = GROW(p0) + 0 * NDENSE;
    const float* g1 = GROW(p1) + 1 * NDENSE;
    const float* g2 = GROW(p2) + 2 * NDENSE;
    const float* g3 = GROW(p3) + 3 * NDENSE;
    const float* g4 = GROW(p4) + 4 * NDENSE;

    const int pg = lane >> 3, jg = lane & 7;
    const int pb = wave ? (56 + 8 * pg) : (8 * pg);
    const float* wgp = w1L + 8 * jg;        // this lane's j-octet in w1L row k (LDS!)

    v2f vp[4][8];
    #pragma unroll
    for (int ip = 0; ip < 4; ip++)
        #pragma unroll
        for (int r = 0; r < 8; r++) vp[ip][r] = (v2f)(0.f);

    float hdot = 0.f;

    for (int qq = 0; qq < 4; qq++) {
        // phase 1 quarter: h for k = 16*qq .. 16*qq+15, written straight to HTQ
        // (R17-validated; bit-identical values/order)
        #pragma unroll
        for (int c = 0; c < 4; c++) {
            const int cc = qq * 4 + c;
            float4 a = *(const float4*)(b0s + cc * 4);                    // uniform
            float4 q;
            q = *(const float4*)(g0 + cc * 4); a.x += q.x; a.y += q.y; a.z += q.z; a.w += q.w;
            q = *(const float4*)(g1 + cc * 4); a.x += q.x; a.y += q.y; a.z += q.z; a.w += q.w;
            q = *(const float4*)(g2 + cc * 4); a.x += q.x; a.y += q.y; a.z += q.z; a.w += q.w;
            q = *(const float4*)(g3 + cc * 4); a.x += q.x; a.y += q.y; a.z += q.z; a.w += q.w;
            q = *(const float4*)(g4 + cc * 4); a.x += q.x; a.y += q.y; a.z += q.z; a.w += q.w;
            float t0 = fast_tanh(a.x), t1 = fast_tanh(a.y), t2 = fast_tanh(a.z), t3 = fast_tanh(a.w);
            if (lane < 60) {
                HTQROW(c * 4 + 0)[pid] = t0;   // b32 writes, consecutive pids -> free
                HTQROW(c * 4 + 1)[pid] = t1;
                HTQROW(c * 4 + 2)[pid] = t2;
                HTQROW(c * 4 + 3)[pid] = t3;
            }
            hdot += t0 * w2s[cc * 4 + 0] + t1 * w2s[cc * 4 + 1]
                  + t2 * w2s[cc * 4 + 2] + t3 * w2s[cc * 4 + 3];
        }
        __syncthreads();                    // HTQ visible to both waves

        // phase 2 quarter: 16 k-steps of V[120x64] = H @ W1 (same k order as R13).
        // w1 now from LDS: 8-lane broadcast groups, banks {0-3,8-11,16-19,24-27} x2
        // per read = 2-way aliasing = free (m136). No vmem traffic in this loop.
        #pragma unroll 4
        for (int kk = 0; kk < KQ; kk++) {
            const v4f ha = *(const v4f*)(&HTQROW(kk)[pb]);
            const v4f hb = *(const v4f*)(&HTQROW(kk)[pb + 4]);
            const v4f wa = *(const v4f*)(wgp + (qq * KQ + kk) * NDENSE);
            const v4f wb = *(const v4f*)(wgp + (qq * KQ + kk) * NDENSE + 4);
            v2f hp[4] = {ha.xy, ha.zw, hb.xy, hb.zw};   // perm pairs
            v2f wp[4] = {wa.xy, wa.zw, wb.xy, wb.zw};   // j pairs
            #pragma unroll
            for (int ip = 0; ip < 4; ip++) {
                PK_FMA_LO(vp[ip][0], hp[ip], wp[0]);
                PK_FMA_HI(vp[ip][1], hp[ip], wp[0]);
                PK_FMA_LO(vp[ip][2], hp[ip], wp[1]);
                PK_FMA_HI(vp[ip][3], hp[ip], wp[1]);
                PK_FMA_LO(vp[ip][4], hp[ip], wp[2]);
                PK_FMA_HI(vp[ip][5], hp[ip], wp[2]);
                PK_FMA_LO(vp[ip][6], hp[ip], wp[3]);
                PK_FMA_HI(vp[ip][7], hp[ip], wp[3]);
            }
        }
        __syncthreads();                    // HTQ reads done before next quarter's park
    }

    double dvh = (double)(sign * hdot);     // sign=0 for lanes 60-63
    #pragma unroll
    for (int off = 32; off > 0; off >>= 1) dvh += __shfl_down(dvh, off, 64);
    if (lane == 0) red_h[s][wave] = dvh;

    // epilogue: lanesum = sum_i sgn_i * sum_r tanh(v[i][r]+b1[j]) * w2[j]
    float4 b1a = *(const float4*)(b1s + 8 * jg);
    float4 b1b = *(const float4*)(b1s + 8 * jg + 4);
    float4 w2a = *(const float4*)(w2s + 8 * jg);
    float4 w2b = *(const float4*)(w2s + 8 * jg + 4);
    const float b1v[8] = {b1a.x, b1a.y, b1a.z, b1a.w, b1b.x, b1b.y, b1b.z, b1b.w};
    const float w2v[8] = {w2a.x, w2a.y, w2a.z, w2a.w, w2b.x, w2b.y, w2b.z, w2b.w};

    float lanesum = 0.f;
    #pragma unroll
    for (int i = 0; i < 8; i++) {
        int p = pb + i;                      // Lehmer parity
        int d0 = p / 24;  int r0 = p - 24 * d0;
        int d1 = r0 / 6;  int r1 = r0 - 6 * d1;
        int d2 = r1 >> 1; int d3 = r1 & 1;
        float sgn = ((d0 + d1 + d2 + d3) & 1) ? -1.f : 1.f;
        if (wave == 1 && pg == 0) sgn = 0.f; // duplicate tile (perms 56-63)
        float si = 0.f;
        #pragma unroll
        for (int r = 0; r < 8; r++) {
            float vir = (i & 1) ? vp[i >> 1][r].y : vp[i >> 1][r].x;
            si = fmaf(fast_tanh(vir + b1v[r]), w2v[r], si);
        }
        lanesum = fmaf(sgn, si, lanesum);
    }

    double dvj = (double)lanesum;
    #pragma unroll
    for (int off = 32; off > 0; off >>= 1) dvj += __shfl_down(dvj, off, 64);
    if (lane == 0) red_j[s][wave] = dvj;
    __syncthreads();

    // ---- inline combine (R13-validated) ----
    if (t == 0) {
        float ps0 = (float)((red_h[0][0] + red_h[0][1]) + (red_j[0][0] + red_j[0][1]));
        float ps1 = (float)((red_h[1][0] + red_h[1][1]) + (red_j[1][0] + red_j[1][1]));
        float jas = 0.f;
        #pragma unroll
        for (int i = 0; i < 2 * NELEC; i++) jas += jterm[i];
        out[b] = logf(fabsf(ps0 * ps1)) - jas;
    }
    // b2 omitted: sum_p sign_p = 0 kills it exactly.
}

extern "C" void kernel_launch(void* const* d_in, const int* in_sizes, int n_in,
                              void* d_out, int out_size, void* d_ws, size_t ws_size,
                              hipStream_t stream) {
    const float* elec_pos = (const float*)d_in[0];
    const float* ion_pos  = (const float*)d_in[1];
    const float* bf_w     = (const float*)d_in[2];
    const float* bf_b     = (const float*)d_in[3];
    const float* w0       = (const float*)d_in[4];
    const float* b0       = (const float*)d_in[5];
    const float* w1       = (const float*)d_in[6];
    const float* b1       = (const float*)d_in[7];
    const float* w2       = (const float*)d_in[8];
    const float* jk       = (const float*)d_in[10];
    float* out = (float*)d_out;

    const int B = in_sizes[0] / (NELEC * DIM);   // 2048

    hipLaunchKernelGGL(antisym_fused,
                       dim3(B), dim3(256), 0, stream,
                       elec_pos, ion_pos, bf_w, bf_b, w0, b0, w1, b1, w2, jk, out, B);
}